// Round 1
// baseline (267.638 us; speedup 1.0000x reference)
//
#include <hip/hip_runtime.h>
#include <hip/hip_bf16.h>
#include <stdint.h>

#define TSEQ 3072
#define DIMM 1024
#define NH   8
#define HD   128

typedef float f32x4 __attribute__((ext_vector_type(4)));
typedef short s16x8 __attribute__((ext_vector_type(8)));
typedef unsigned short u16;

// ---------- helpers ----------
static __device__ __forceinline__ u16 f2b(float f) {
  union { float f; unsigned u; } a; a.f = f;
  unsigned r = a.u + 0x7FFFu + ((a.u >> 16) & 1u);   // RNE
  return (u16)(r >> 16);
}
static __device__ __forceinline__ float b2f(u16 u) {
  union { unsigned u; float f; } a; a.u = ((unsigned)u) << 16;
  return a.f;
}
static __device__ __forceinline__ void gload_lds16(const void* g, void* l) {
  __builtin_amdgcn_global_load_lds(
      (const __attribute__((address_space(1))) unsigned int*)(unsigned long long)g,
      (__attribute__((address_space(3))) unsigned int*)(unsigned long long)l,
      16, 0, 0);
}

// ---------- 0: f32 -> bf16 conversion (w scaled by sa_lambdas) ----------
__global__ __launch_bounds__(256) void k_convert(
    const float* __restrict__ x, const float* __restrict__ w,
    const float* __restrict__ lam,
    u16* __restrict__ xb, u16* __restrict__ wb)
{
  const int NX = TSEQ * DIMM;          // 3145728
  const int NW = 4 * DIMM * DIMM;      // 4194304
  const float l0 = lam[0], l1 = lam[1];
  const int n4 = (NX + NW) >> 2;
  for (int j = blockIdx.x * 256 + threadIdx.x; j < n4; j += gridDim.x * 256) {
    const int e = j << 2;
    float4 v; u16* dst; float s;
    if (e < NX) { v = *(const float4*)(x + e); dst = xb + e; s = 1.f; }
    else {
      const int we = e - NX;
      v = *(const float4*)(w + we);
      dst = wb + we;
      s = (we < 3 * DIMM * DIMM) ? l0 : l1;
    }
    dst[0] = f2b(v.x * s); dst[1] = f2b(v.y * s);
    dst[2] = f2b(v.z * s); dst[3] = f2b(v.w * s);
  }
}

// ---------- NT GEMM: C[M][N] = A[M][K] * B[N][K]^T  (bf16 in, f32 out) ----------
// m97 structure: 128x128 tile, BK=64, 4 waves (2x2), 4x4 16x16x32 frags/wave.
__global__ __launch_bounds__(256) void k_gemm_nt(
    const u16* __restrict__ A, const u16* __restrict__ B,
    float* __restrict__ C, int M, int N, int K)
{
  __shared__ u16 As[128 * 64];
  __shared__ u16 Bs[128 * 64];
  const int tid = threadIdx.x;
  const int lane = tid & 63, wv = tid >> 6;
  const int m0 = blockIdx.y * 128, n0 = blockIdx.x * 128;
  const int wm = (wv >> 1) * 64, wn = (wv & 1) * 64;
  const int c0 = lane & 15, r0 = (lane >> 4) * 4, koff = (lane >> 4) * 8;

  f32x4 acc[4][4];
  #pragma unroll
  for (int i = 0; i < 4; i++)
    #pragma unroll
    for (int j = 0; j < 4; j++) acc[i][j] = (f32x4){0.f, 0.f, 0.f, 0.f};

  const int srow = tid >> 3;           // 0..31
  const int scol = (tid & 7) * 8;      // elem offset in row
  const size_t a_base = (size_t)(m0 + srow) * K + scol;
  const size_t b_base = (size_t)(n0 + srow) * K + scol;

  for (int kt = 0; kt < K; kt += 64) {
    __syncthreads();
    #pragma unroll
    for (int i = 0; i < 4; i++) {
      gload_lds16(A + a_base + (size_t)(i * 32) * K + kt, (char*)As + i * 4096 + tid * 16);
      gload_lds16(B + b_base + (size_t)(i * 32) * K + kt, (char*)Bs + i * 4096 + tid * 16);
    }
    __syncthreads();
    #pragma unroll
    for (int kk = 0; kk < 2; kk++) {
      s16x8 af[4], bf[4];
      #pragma unroll
      for (int i = 0; i < 4; i++) {
        af[i] = *(const s16x8*)&As[(wm + i * 16 + c0) * 64 + kk * 32 + koff];
        bf[i] = *(const s16x8*)&Bs[(wn + i * 16 + c0) * 64 + kk * 32 + koff];
      }
      #pragma unroll
      for (int i = 0; i < 4; i++)
        #pragma unroll
        for (int j = 0; j < 4; j++)
          acc[i][j] = __builtin_amdgcn_mfma_f32_16x16x32_bf16(af[i], bf[j], acc[i][j], 0, 0, 0);
    }
  }
  #pragma unroll
  for (int i = 0; i < 4; i++)
    #pragma unroll
    for (int j = 0; j < 4; j++) {
      float* cp = C + (size_t)(m0 + wm + i * 16 + r0) * N + n0 + wn + j * 16 + c0;
      #pragma unroll
      for (int r = 0; r < 4; r++) cp[(size_t)r * N] = acc[i][j][r];
    }
}

// ---------- 2: per-(t,h) prep: rmsnorm, rotary, k-prev mix, ve gate, attn gate ----------
__global__ __launch_bounds__(256) void k_prep(
    const float* __restrict__ qkv, const float* __restrict__ x,
    const float* __restrict__ ve, const float* __restrict__ cosb,
    const float* __restrict__ sinb, const float* __restrict__ gwa,
    const float* __restrict__ gwv,
    u16* __restrict__ Qg, u16* __restrict__ Kg, u16* __restrict__ VTg,
    float* __restrict__ gateA)
{
  const int gid = blockIdx.x * 4 + (threadIdx.x >> 6);
  const int lane = threadIdx.x & 63;
  const int h = gid / TSEQ;
  const int t = gid - h * TSEQ;
  const int tp = (t == 0) ? 0 : t - 1;

  const float* qrow = qkv + (size_t)t * (3 * DIMM) + h * HD;
  const float* krow = qrow + DIMM;
  const float* vrow = qrow + 2 * DIMM;
  const float* prow = qkv + (size_t)tp * (3 * DIMM) + DIMM + h * HD;

  float q1 = qrow[lane], q2 = qrow[lane + 64];
  float k1 = krow[lane], k2 = krow[lane + 64];
  float p1 = prow[lane], p2 = prow[lane + 64];

  float sq = q1 * q1 + q2 * q2, sk = k1 * k1 + k2 * k2, sp = p1 * p1 + p2 * p2;
  #pragma unroll
  for (int m = 1; m < 64; m <<= 1) {
    sq += __shfl_xor(sq, m, 64);
    sk += __shfl_xor(sk, m, 64);
    sp += __shfl_xor(sp, m, 64);
  }
  const float rq = rsqrtf(sq * (1.f / 128.f) + 1e-6f);
  const float rk = rsqrtf(sk * (1.f / 128.f) + 1e-6f);
  const float rp = rsqrtf(sp * (1.f / 128.f) + 1e-6f);
  q1 *= rq; q2 *= rq; k1 *= rk; k2 *= rk; p1 *= rp; p2 *= rp;

  const float c  = cosb[t * 64 + lane],  s  = sinb[t * 64 + lane];
  const float cp = cosb[tp * 64 + lane], spv = sinb[tp * 64 + lane];
  const float qo1 =  q1 * c + q2 * s,   qo2 = -q1 * s + q2 * c;
  const float ko1 =  k1 * c + k2 * s,   ko2 = -k1 * s + k2 * c;
  const float po1 =  p1 * cp + p2 * spv, po2 = -p1 * spv + p2 * cp;
  // channels [0:32)+[64:96) from k(t); [32:64)+[96:128) from k(t-1)
  const float m1 = (lane < 32) ? ko1 : po1;
  const float m2 = (lane < 32) ? ko2 : po2;

  const size_t qkbase = ((size_t)h * TSEQ + t) * HD + lane;
  Qg[qkbase] = f2b(qo1); Qg[qkbase + 64] = f2b(qo2);
  Kg[qkbase] = f2b(m1);  Kg[qkbase + 64] = f2b(m2);

  float dv = 0.f, da = 0.f;
  #pragma unroll
  for (int g = 0; g < 16; g++) {
    const float xv = x[(size_t)t * DIMM + g];
    dv += xv * gwv[h * 16 + g];
    da += xv * gwa[h * 16 + g];
  }
  const float vg = 2.f / (1.f + __expf(-dv));
  const float v1 = vrow[lane]      + vg * ve[(size_t)t * DIMM + h * HD + lane];
  const float v2 = vrow[lane + 64] + vg * ve[(size_t)t * DIMM + h * HD + lane + 64];
  VTg[((size_t)h * HD + lane) * TSEQ + t]        = f2b(v1);
  VTg[((size_t)h * HD + lane + 64) * TSEQ + t]   = f2b(v2);
  if (lane == 0) gateA[h * TSEQ + t] = 1.f / (1.f + __expf(-da));
}

// ---------- 3: flash attention (windowed causal + segments), gated epilogue ----------
__global__ __launch_bounds__(256) void k_attn(
    const u16* __restrict__ Qg, const u16* __restrict__ Kg,
    const u16* __restrict__ VTg, const float* __restrict__ gateA,
    const int* __restrict__ seg, const int* __restrict__ bmp,
    u16* __restrict__ Y)
{
  __shared__ u16 Ks[64 * HD];     // [key][dim], XOR-swizzled rows (256B rows)
  __shared__ u16 Vs[HD * 64];     // [dim][key], XOR-swizzled rows (128B rows)
  __shared__ u16 Ps[4][16 * 64];  // per-wave P, XOR-swizzled (128B rows)

  const int tid = threadIdx.x, lane = tid & 63, wv = tid >> 6;
  const int h = blockIdx.y;
  const int q0 = blockIdx.x * 64;
  const int qw = q0 + wv * 16;
  const int bm = bmp[0];
  const int r0 = (lane >> 4) * 4, c0 = lane & 15;
  const int koff = (lane >> 4) * 8;

  // Q fragments (A-layout: row = lane&15, k = (lane>>4)*8 + b)
  s16x8 qf[4];
  {
    const u16* qp = Qg + ((size_t)h * TSEQ + qw + c0) * HD + koff;
    #pragma unroll
    for (int kk = 0; kk < 4; kk++) qf[kk] = *(const s16x8*)(qp + kk * 32);
  }

  int qt[4]; int qseg[4]; float qgate[4];
  #pragma unroll
  for (int r = 0; r < 4; r++) {
    qt[r] = qw + r0 + r;
    qseg[r] = seg[qt[r]];
    qgate[r] = gateA[h * TSEQ + qt[r]];
  }

  f32x4 o[8];
  #pragma unroll
  for (int i = 0; i < 8; i++) o[i] = (f32x4){0.f, 0.f, 0.f, 0.f};
  float mrow[4] = {-1e30f, -1e30f, -1e30f, -1e30f};
  float lrow[4] = {0.f, 0.f, 0.f, 0.f};

  int s_begin = q0 - bm; if (s_begin < 0) s_begin = 0;
  s_begin &= ~63;

  for (int s0 = s_begin; s0 < q0 + 64; s0 += 64) {
    __syncthreads();
    #pragma unroll
    for (int i = 0; i < 4; i++) {
      const int L = tid * 16 + i * 4096;
      const int kr = L >> 8;
      const int kc = (L & 255) ^ ((kr & 7) << 4);
      gload_lds16(Kg + ((size_t)h * TSEQ + s0 + kr) * HD + (kc >> 1), (char*)Ks + L);
      const int vr = L >> 7;
      const int vc = (L & 127) ^ ((vr & 7) << 4);
      gload_lds16(VTg + ((size_t)h * HD + vr) * TSEQ + s0 + (vc >> 1), (char*)Vs + L);
    }
    __syncthreads();

    // S = Q K^T
    f32x4 sv[4];
    #pragma unroll
    for (int n = 0; n < 4; n++) {
      sv[n] = (f32x4){0.f, 0.f, 0.f, 0.f};
      #pragma unroll
      for (int kk = 0; kk < 4; kk++) {
        const int krow = n * 16 + c0;
        const int kbyte = (krow << 8) + ((((kk * 32 + koff) << 1)) ^ ((krow & 7) << 4));
        const s16x8 kf = *(const s16x8*)((const char*)Ks + kbyte);
        sv[n] = __builtin_amdgcn_mfma_f32_16x16x32_bf16(qf[kk], kf, sv[n], 0, 0, 0);
      }
    }
    // scale + mask
    #pragma unroll
    for (int n = 0; n < 4; n++) {
      const int key = s0 + n * 16 + c0;
      const int ks = seg[key];
      #pragma unroll
      for (int r = 0; r < 4; r++) {
        const bool ok = (key <= qt[r]) && (key >= qt[r] - bm) && (ks == qseg[r]);
        sv[n][r] = ok ? sv[n][r] * 0.1f : -1e30f;
      }
    }
    // row-max over 4 frags then across the 16-lane group
    float pm[4];
    #pragma unroll
    for (int r = 0; r < 4; r++)
      pm[r] = fmaxf(fmaxf(sv[0][r], sv[1][r]), fmaxf(sv[2][r], sv[3][r]));
    #pragma unroll
    for (int m = 1; m < 16; m <<= 1)
      #pragma unroll
      for (int r = 0; r < 4; r++) pm[r] = fmaxf(pm[r], __shfl_xor(pm[r], m, 64));

    float scl[4], rs[4];
    #pragma unroll
    for (int r = 0; r < 4; r++) {
      const float mn = fmaxf(mrow[r], pm[r]);
      scl[r] = __expf(mrow[r] - mn);
      mrow[r] = mn;
      rs[r] = 0.f;
    }
    u16 pb[4][4];
    #pragma unroll
    for (int n = 0; n < 4; n++)
      #pragma unroll
      for (int r = 0; r < 4; r++) {
        const float p = (sv[n][r] < -0.5e30f) ? 0.f : __expf(sv[n][r] - mrow[r]);
        rs[r] += p;
        pb[n][r] = f2b(p);
      }
    #pragma unroll
    for (int m = 1; m < 16; m <<= 1)
      #pragma unroll
      for (int r = 0; r < 4; r++) rs[r] += __shfl_xor(rs[r], m, 64);
    #pragma unroll
    for (int r = 0; r < 4; r++) lrow[r] = lrow[r] * scl[r] + rs[r];
    #pragma unroll
    for (int i = 0; i < 8; i++)
      #pragma unroll
      for (int r = 0; r < 4; r++) o[i][r] *= scl[r];

    // P -> LDS (swizzled), then re-fragment as PV A-operand
    char* pbase = (char*)Ps[wv];
    #pragma unroll
    for (int n = 0; n < 4; n++)
      #pragma unroll
      for (int r = 0; r < 4; r++) {
        const int row = r0 + r;
        const int byt = (row << 7) + ((((n * 16 + c0) << 1)) ^ ((row & 7) << 4));
        *(u16*)(pbase + byt) = pb[n][r];
      }
    #pragma unroll
    for (int kc = 0; kc < 2; kc++) {
      const int pbyte = (c0 << 7) + ((((kc * 32 + koff) << 1)) ^ ((c0 & 7) << 4));
      const s16x8 pf = *(const s16x8*)(pbase + pbyte);
      #pragma unroll
      for (int nf = 0; nf < 8; nf++) {
        const int vrow = nf * 16 + c0;
        const int vbyte = (vrow << 7) + ((((kc * 32 + koff) << 1)) ^ ((vrow & 7) << 4));
        const s16x8 vf = *(const s16x8*)((const char*)Vs + vbyte);
        o[nf] = __builtin_amdgcn_mfma_f32_16x16x32_bf16(pf, vf, o[nf], 0, 0, 0);
      }
    }
  }

  #pragma unroll
  for (int r = 0; r < 4; r++) {
    const float inv = (lrow[r] > 0.f) ? (qgate[r] / lrow[r]) : 0.f;
    #pragma unroll
    for (int nf = 0; nf < 8; nf++)
      Y[(size_t)qt[r] * DIMM + h * HD + nf * 16 + c0] = f2b(o[nf][r] * inv);
  }
}

// ---------- launch ----------
extern "C" void kernel_launch(void* const* d_in, const int* in_sizes, int n_in,
                              void* d_out, int out_size, void* d_ws, size_t ws_size,
                              hipStream_t stream) {
  const float* x    = (const float*)d_in[0];
  const float* qkvo = (const float*)d_in[1];
  const float* lam  = (const float*)d_in[2];
  const float* ve   = (const float*)d_in[3];
  const float* gwa  = (const float*)d_in[4];
  const float* gwv  = (const float*)d_in[5];
  const float* cosb = (const float*)d_in[6];
  const float* sinb = (const float*)d_in[7];
  const int*   seg  = (const int*)d_in[8];
  const int*   bm   = (const int*)d_in[9];
  float* out = (float*)d_out;

  char* ws = (char*)d_ws;
  size_t off = 0;
  auto alloc = [&](size_t bytes) -> void* {
    void* p = ws + off;
    off += (bytes + 255) & ~(size_t)255;
    return p;
  };
  u16*   xb    = (u16*)alloc((size_t)TSEQ * DIMM * 2);
  u16*   wb    = (u16*)alloc((size_t)4 * DIMM * DIMM * 2);
  float* qkv   = (float*)alloc((size_t)TSEQ * 3 * DIMM * 4);
  u16*   Qg    = (u16*)alloc((size_t)NH * TSEQ * HD * 2);
  u16*   Kg    = (u16*)alloc((size_t)NH * TSEQ * HD * 2);
  u16*   VTg   = (u16*)alloc((size_t)NH * HD * TSEQ * 2);
  float* gateA = (float*)alloc((size_t)NH * TSEQ * 4);
  u16*   Yg    = (u16*)alloc((size_t)TSEQ * DIMM * 2);

  k_convert<<<2048, 256, 0, stream>>>(x, qkvo, lam, xb, wb);
  k_gemm_nt<<<dim3(24, 24), 256, 0, stream>>>(xb, wb, qkv, TSEQ, 3 * DIMM, DIMM);
  k_prep<<<NH * TSEQ / 4, 256, 0, stream>>>(qkv, x, ve, cosb, sinb, gwa, gwv, Qg, Kg, VTg, gateA);
  k_attn<<<dim3(TSEQ / 64, NH), 256, 0, stream>>>(Qg, Kg, VTg, gateA, seg, bm, Yg);
  k_gemm_nt<<<dim3(DIMM / 128, 24), 256, 0, stream>>>(Yg, wb + (size_t)3 * DIMM * DIMM, out, TSEQ, DIMM, DIMM);
}

// Round 2
// 245.828 us; speedup vs baseline: 1.0887x; 1.0887x over previous
//
#include <hip/hip_runtime.h>
#include <hip/hip_bf16.h>
#include <stdint.h>

#define TSEQ 3072
#define DIMM 1024
#define NH   8
#define HD   128
#define QBLK 32

typedef float f32x4 __attribute__((ext_vector_type(4)));
typedef short s16x8 __attribute__((ext_vector_type(8)));
typedef unsigned short u16;

// ---------- helpers ----------
static __device__ __forceinline__ u16 f2b(float f) {
  union { float f; unsigned u; } a; a.f = f;
  unsigned r = a.u + 0x7FFFu + ((a.u >> 16) & 1u);   // RNE
  return (u16)(r >> 16);
}
static __device__ __forceinline__ void gload_lds16(const void* g, void* l) {
  __builtin_amdgcn_global_load_lds(
      (const __attribute__((address_space(1))) unsigned int*)(unsigned long long)g,
      (__attribute__((address_space(3))) unsigned int*)(unsigned long long)l,
      16, 0, 0);
}
static __device__ __forceinline__ void bar() {
  asm volatile("" ::: "memory");
  __builtin_amdgcn_s_barrier();
  asm volatile("" ::: "memory");
}
#define SWAIT(n) asm volatile("s_waitcnt vmcnt(" #n ")" ::: "memory")

// ---------- 0: f32 -> bf16 conversion (w scaled by sa_lambdas) ----------
__global__ __launch_bounds__(256) void k_convert(
    const float* __restrict__ x, const float* __restrict__ w,
    const float* __restrict__ lam,
    u16* __restrict__ xb, u16* __restrict__ wb)
{
  const int NX = TSEQ * DIMM;
  const int NW = 4 * DIMM * DIMM;
  const float l0 = lam[0], l1 = lam[1];
  const int n4 = (NX + NW) >> 2;
  for (int j = blockIdx.x * 256 + threadIdx.x; j < n4; j += gridDim.x * 256) {
    const int e = j << 2;
    float4 v; u16* dst; float s;
    if (e < NX) { v = *(const float4*)(x + e); dst = xb + e; s = 1.f; }
    else {
      const int we = e - NX;
      v = *(const float4*)(w + we);
      dst = wb + we;
      s = (we < 3 * DIMM * DIMM) ? l0 : l1;
    }
    dst[0] = f2b(v.x * s); dst[1] = f2b(v.y * s);
    dst[2] = f2b(v.z * s); dst[3] = f2b(v.w * s);
  }
}

// ---------- NT GEMM: C[M][N] = A[M][K] * B[N][K]^T  (bf16 in, f32 out) ----------
__global__ __launch_bounds__(256) void k_gemm_nt(
    const u16* __restrict__ A, const u16* __restrict__ B,
    float* __restrict__ C, int M, int N, int K)
{
  __shared__ u16 As[128 * 64];
  __shared__ u16 Bs[128 * 64];
  const int tid = threadIdx.x;
  const int lane = tid & 63, wv = tid >> 6;
  const int m0 = blockIdx.y * 128, n0 = blockIdx.x * 128;
  const int wm = (wv >> 1) * 64, wn = (wv & 1) * 64;
  const int c0 = lane & 15, r0 = (lane >> 4) * 4, koff = (lane >> 4) * 8;

  f32x4 acc[4][4];
  #pragma unroll
  for (int i = 0; i < 4; i++)
    #pragma unroll
    for (int j = 0; j < 4; j++) acc[i][j] = (f32x4){0.f, 0.f, 0.f, 0.f};

  const int srow = tid >> 3;
  const int scol = (tid & 7) * 8;
  const size_t a_base = (size_t)(m0 + srow) * K + scol;
  const size_t b_base = (size_t)(n0 + srow) * K + scol;

  for (int kt = 0; kt < K; kt += 64) {
    __syncthreads();
    #pragma unroll
    for (int i = 0; i < 4; i++) {
      gload_lds16(A + a_base + (size_t)(i * 32) * K + kt, (char*)As + i * 4096 + tid * 16);
      gload_lds16(B + b_base + (size_t)(i * 32) * K + kt, (char*)Bs + i * 4096 + tid * 16);
    }
    __syncthreads();
    #pragma unroll
    for (int kk = 0; kk < 2; kk++) {
      s16x8 af[4], bf[4];
      #pragma unroll
      for (int i = 0; i < 4; i++) {
        af[i] = *(const s16x8*)&As[(wm + i * 16 + c0) * 64 + kk * 32 + koff];
        bf[i] = *(const s16x8*)&Bs[(wn + i * 16 + c0) * 64 + kk * 32 + koff];
      }
      #pragma unroll
      for (int i = 0; i < 4; i++)
        #pragma unroll
        for (int j = 0; j < 4; j++)
          acc[i][j] = __builtin_amdgcn_mfma_f32_16x16x32_bf16(af[i], bf[j], acc[i][j], 0, 0, 0);
    }
  }
  #pragma unroll
  for (int i = 0; i < 4; i++)
    #pragma unroll
    for (int j = 0; j < 4; j++) {
      float* cp = C + (size_t)(m0 + wm + i * 16 + r0) * N + n0 + wn + j * 16 + c0;
      #pragma unroll
      for (int r = 0; r < 4; r++) cp[(size_t)r * N] = acc[i][j][r];
    }
}

// ---------- 2: per-(t,h) prep ----------
__global__ __launch_bounds__(256) void k_prep(
    const float* __restrict__ qkv, const float* __restrict__ x,
    const float* __restrict__ ve, const float* __restrict__ cosb,
    const float* __restrict__ sinb, const float* __restrict__ gwa,
    const float* __restrict__ gwv,
    u16* __restrict__ Qg, u16* __restrict__ Kg, u16* __restrict__ Vtmp,
    float* __restrict__ gateA)
{
  const int gid = blockIdx.x * 4 + (threadIdx.x >> 6);
  const int lane = threadIdx.x & 63;
  const int h = gid / TSEQ;
  const int t = gid - h * TSEQ;
  const int tp = (t == 0) ? 0 : t - 1;

  const float* qrow = qkv + (size_t)t * (3 * DIMM) + h * HD;
  const float* krow = qrow + DIMM;
  const float* vrow = qrow + 2 * DIMM;
  const float* prow = qkv + (size_t)tp * (3 * DIMM) + DIMM + h * HD;

  float q1 = qrow[lane], q2 = qrow[lane + 64];
  float k1 = krow[lane], k2 = krow[lane + 64];
  float p1 = prow[lane], p2 = prow[lane + 64];

  float sq = q1 * q1 + q2 * q2, sk = k1 * k1 + k2 * k2, sp = p1 * p1 + p2 * p2;
  #pragma unroll
  for (int m = 1; m < 64; m <<= 1) {
    sq += __shfl_xor(sq, m, 64);
    sk += __shfl_xor(sk, m, 64);
    sp += __shfl_xor(sp, m, 64);
  }
  const float rq = rsqrtf(sq * (1.f / 128.f) + 1e-6f);
  const float rk = rsqrtf(sk * (1.f / 128.f) + 1e-6f);
  const float rp = rsqrtf(sp * (1.f / 128.f) + 1e-6f);
  q1 *= rq; q2 *= rq; k1 *= rk; k2 *= rk; p1 *= rp; p2 *= rp;

  const float c  = cosb[t * 64 + lane],  s  = sinb[t * 64 + lane];
  const float cp = cosb[tp * 64 + lane], spv = sinb[tp * 64 + lane];
  const float qo1 =  q1 * c + q2 * s,   qo2 = -q1 * s + q2 * c;
  const float ko1 =  k1 * c + k2 * s,   ko2 = -k1 * s + k2 * c;
  const float po1 =  p1 * cp + p2 * spv, po2 = -p1 * spv + p2 * cp;
  const float m1 = (lane < 32) ? ko1 : po1;
  const float m2 = (lane < 32) ? ko2 : po2;

  const size_t qkbase = ((size_t)h * TSEQ + t) * HD + lane;
  Qg[qkbase] = f2b(qo1); Qg[qkbase + 64] = f2b(qo2);
  Kg[qkbase] = f2b(m1);  Kg[qkbase + 64] = f2b(m2);

  float dv = 0.f, da = 0.f;
  #pragma unroll
  for (int g = 0; g < 16; g++) {
    const float xv = x[(size_t)t * DIMM + g];
    dv += xv * gwv[h * 16 + g];
    da += xv * gwa[h * 16 + g];
  }
  const float vg = 2.f / (1.f + __expf(-dv));
  const float v1 = vrow[lane]      + vg * ve[(size_t)t * DIMM + h * HD + lane];
  const float v2 = vrow[lane + 64] + vg * ve[(size_t)t * DIMM + h * HD + lane + 64];
  u16* vt = Vtmp + ((size_t)h * TSEQ + t) * HD;
  vt[lane] = f2b(v1); vt[lane + 64] = f2b(v2);
  if (lane == 0) gateA[h * TSEQ + t] = 1.f / (1.f + __expf(-da));
}

// ---------- 2b: V transpose  Vtmp[h][t][d] -> VT[h][d][t]  (64x64 LDS tiles) ----------
__global__ __launch_bounds__(256) void k_vtrans(
    const u16* __restrict__ Vtmp, u16* __restrict__ VT)
{
  __shared__ u16 tile[64][68];
  const int h  = blockIdx.z;
  const int d0 = blockIdx.y * 64;
  const int t0 = blockIdx.x * 64;
  const int tid = threadIdx.x;
  const int rr = tid >> 3, cc = (tid & 7) * 8;
  #pragma unroll
  for (int p = 0; p < 2; p++) {
    const int r = rr + p * 32;
    const s16x8 v = *(const s16x8*)(Vtmp + ((size_t)h * TSEQ + t0 + r) * HD + d0 + cc);
    #pragma unroll
    for (int j = 0; j < 8; j++) tile[r][cc + j] = ((const u16*)&v)[j];
  }
  __syncthreads();
  #pragma unroll
  for (int p = 0; p < 2; p++) {
    const int r = rr + p * 32;                 // output d-row (within tile)
    s16x8 v;
    #pragma unroll
    for (int j = 0; j < 8; j++) ((u16*)&v)[j] = tile[cc + j][r];
    *(s16x8*)(VT + ((size_t)h * HD + d0 + r) * TSEQ + t0 + cc) = v;
  }
}

// ---------- 3: flash attention, QBLK=32, 2 waves, pipelined K-dbuf ----------
__global__ __launch_bounds__(128) void k_attn(
    const u16* __restrict__ Qg, const u16* __restrict__ Kg,
    const u16* __restrict__ VTg, const float* __restrict__ gateA,
    const int* __restrict__ seg, const int* __restrict__ bmp,
    u16* __restrict__ Y)
{
  __shared__ u16 Ks[2][64 * HD];   // 2 x 16KB, 256B rows, XOR-swizzled
  __shared__ u16 Vs[HD * 64];      // 16KB, 128B rows, XOR-swizzled
  __shared__ u16 Ps[2][16 * 64];   // per-wave P, 128B rows, XOR-swizzled

  const int tid = threadIdx.x, lane = tid & 63, wv = tid >> 6;
  const int h = blockIdx.y;
  const int q0 = blockIdx.x * QBLK;
  const int qw = q0 + wv * 16;
  const int bm = bmp[0];
  const int r0 = (lane >> 4) * 4, c0 = lane & 15;
  const int koff = (lane >> 4) * 8;

  // Q fragments
  s16x8 qf[4];
  {
    const u16* qp = Qg + ((size_t)h * TSEQ + qw + c0) * HD + koff;
    #pragma unroll
    for (int kk = 0; kk < 4; kk++) qf[kk] = *(const s16x8*)(qp + kk * 32);
  }

  int qt[4]; int qseg[4]; float qgate[4];
  #pragma unroll
  for (int r = 0; r < 4; r++) {
    qt[r] = qw + r0 + r;
    qseg[r] = seg[qt[r]];
    qgate[r] = gateA[h * TSEQ + qt[r]];
  }
  const int segw_lo = seg[qw], segw_hi = seg[qw + 15];

  // segment-aware lower bound (seg is monotone non-decreasing)
  const int seg_q = seg[q0];
  int lo = 0, hi = q0;
  while (lo < hi) { const int mid = (lo + hi) >> 1; if (seg[mid] < seg_q) lo = mid + 1; else hi = mid; }
  int s_begin = q0 - bm; if (s_begin < lo) s_begin = lo; if (s_begin < 0) s_begin = 0;
  s_begin &= ~63;
  const int s_end = q0 + QBLK;

  f32x4 o[8];
  #pragma unroll
  for (int i = 0; i < 8; i++) o[i] = (f32x4){0.f, 0.f, 0.f, 0.f};
  float mrow[4] = {-1e30f, -1e30f, -1e30f, -1e30f};
  float lrow[4] = {0.f, 0.f, 0.f, 0.f};

  auto stageK = [&](int buf, int s0k) {
    #pragma unroll
    for (int i = 0; i < 8; i++) {
      const int L = tid * 16 + i * 2048;
      const int kr = L >> 8;
      const int kc = (L & 255) ^ ((kr & 7) << 4);
      gload_lds16(Kg + ((size_t)h * TSEQ + s0k + kr) * HD + (kc >> 1), (char*)Ks[buf] + L);
    }
  };
  auto stageV = [&](int s0v) {
    #pragma unroll
    for (int i = 0; i < 8; i++) {
      const int L = tid * 16 + i * 2048;
      const int vr = L >> 7;
      const int vc = (L & 127) ^ ((vr & 7) << 4);
      gload_lds16(VTg + ((size_t)h * HD + vr) * TSEQ + s0v + (vc >> 1), (char*)Vs + L);
    }
  };

  stageK(0, s_begin);          // prologue: first K tile in flight
  int cur = 0;

  for (int s0 = s_begin; s0 < s_end; s0 += 64) {
    bar();                      // (c) PV(t-1) done -> Vs reusable
    stageV(s0);                 // 8 loads
    int sn = s0 + 64; if (sn >= s_end) sn = s0;
    stageK(cur ^ 1, sn);        // 8 loads
    SWAIT(16);                  // K(s0) landed; V(s0)+K(next) still in flight
    bar();                      // (a)

    // S = Q K^T from Ks[cur]
    const char* kbase = (const char*)Ks[cur];
    f32x4 sv[4];
    #pragma unroll
    for (int n = 0; n < 4; n++) {
      sv[n] = (f32x4){0.f, 0.f, 0.f, 0.f};
      const int krow = n * 16 + c0;
      #pragma unroll
      for (int kk = 0; kk < 4; kk++) {
        const int kbyte = (krow << 8) + ((((kk * 32 + koff) << 1)) ^ ((krow & 7) << 4));
        const s16x8 kf = *(const s16x8*)(kbase + kbyte);
        sv[n] = __builtin_amdgcn_mfma_f32_16x16x32_bf16(qf[kk], kf, sv[n], 0, 0, 0);
      }
    }

    // mask (skip for interior tiles)
    const bool interior = (s0 + 64 <= qw) && (s0 >= qw + 15 - bm) &&
                          (seg[s0] == seg[s0 + 63]) && (seg[s0] == segw_lo) &&
                          (segw_lo == segw_hi);
    if (interior) {
      #pragma unroll
      for (int n = 0; n < 4; n++)
        #pragma unroll
        for (int r = 0; r < 4; r++) sv[n][r] *= 0.1f;
    } else {
      #pragma unroll
      for (int n = 0; n < 4; n++) {
        const int key = s0 + n * 16 + c0;
        const int ks = seg[key];
        #pragma unroll
        for (int r = 0; r < 4; r++) {
          const bool ok = (key <= qt[r]) && (key >= qt[r] - bm) && (ks == qseg[r]);
          sv[n][r] = ok ? sv[n][r] * 0.1f : -1e30f;
        }
      }
    }

    // online softmax
    float pm[4];
    #pragma unroll
    for (int r = 0; r < 4; r++)
      pm[r] = fmaxf(fmaxf(sv[0][r], sv[1][r]), fmaxf(sv[2][r], sv[3][r]));
    #pragma unroll
    for (int m = 1; m < 16; m <<= 1)
      #pragma unroll
      for (int r = 0; r < 4; r++) pm[r] = fmaxf(pm[r], __shfl_xor(pm[r], m, 64));

    float scl[4], rs[4];
    #pragma unroll
    for (int r = 0; r < 4; r++) {
      const float mn = fmaxf(mrow[r], pm[r]);
      scl[r] = __expf(mrow[r] - mn);
      mrow[r] = mn;
      rs[r] = 0.f;
    }
    u16 pb[4][4];
    #pragma unroll
    for (int n = 0; n < 4; n++)
      #pragma unroll
      for (int r = 0; r < 4; r++) {
        const float p = (sv[n][r] < -0.5e30f) ? 0.f : __expf(sv[n][r] - mrow[r]);
        rs[r] += p;
        pb[n][r] = f2b(p);
      }
    #pragma unroll
    for (int m = 1; m < 16; m <<= 1)
      #pragma unroll
      for (int r = 0; r < 4; r++) rs[r] += __shfl_xor(rs[r], m, 64);
    #pragma unroll
    for (int r = 0; r < 4; r++) lrow[r] = lrow[r] * scl[r] + rs[r];
    #pragma unroll
    for (int i = 0; i < 8; i++)
      #pragma unroll
      for (int r = 0; r < 4; r++) o[i][r] *= scl[r];

    // P -> per-wave LDS (swizzled), re-fragment as PV A-operand
    char* pbase = (char*)Ps[wv];
    #pragma unroll
    for (int n = 0; n < 4; n++)
      #pragma unroll
      for (int r = 0; r < 4; r++) {
        const int row = r0 + r;
        const int byt = (row << 7) + ((((n * 16 + c0) << 1)) ^ ((row & 7) << 4));
        *(u16*)(pbase + byt) = pb[n][r];
      }

    SWAIT(8);                   // V(s0) landed; K(next) still in flight
    bar();                      // (b)

    #pragma unroll
    for (int kc = 0; kc < 2; kc++) {
      const int pbyte = (c0 << 7) + ((((kc * 32 + koff) << 1)) ^ ((c0 & 7) << 4));
      const s16x8 pf = *(const s16x8*)(pbase + pbyte);
      #pragma unroll
      for (int nf = 0; nf < 8; nf++) {
        const int vrow = nf * 16 + c0;
        const int vbyte = (vrow << 7) + ((((kc * 32 + koff) << 1)) ^ ((vrow & 7) << 4));
        const s16x8 vf = *(const s16x8*)((const char*)Vs + vbyte);
        o[nf] = __builtin_amdgcn_mfma_f32_16x16x32_bf16(pf, vf, o[nf], 0, 0, 0);
      }
    }
    cur ^= 1;
  }

  SWAIT(0);                     // drain trailing prefetch before LDS dealloc

  #pragma unroll
  for (int r = 0; r < 4; r++) {
    const float inv = (lrow[r] > 0.f) ? (qgate[r] / lrow[r]) : 0.f;
    #pragma unroll
    for (int nf = 0; nf < 8; nf++)
      Y[(size_t)qt[r] * DIMM + h * HD + nf * 16 + c0] = f2b(o[nf][r] * inv);
  }
}

// ---------- launch ----------
extern "C" void kernel_launch(void* const* d_in, const int* in_sizes, int n_in,
                              void* d_out, int out_size, void* d_ws, size_t ws_size,
                              hipStream_t stream) {
  const float* x    = (const float*)d_in[0];
  const float* qkvo = (const float*)d_in[1];
  const float* lam  = (const float*)d_in[2];
  const float* ve   = (const float*)d_in[3];
  const float* gwa  = (const float*)d_in[4];
  const float* gwv  = (const float*)d_in[5];
  const float* cosb = (const float*)d_in[6];
  const float* sinb = (const float*)d_in[7];
  const int*   seg  = (const int*)d_in[8];
  const int*   bm   = (const int*)d_in[9];
  float* out = (float*)d_out;

  char* ws = (char*)d_ws;
  size_t off = 0;
  auto alloc = [&](size_t bytes) -> void* {
    void* p = ws + off;
    off += (bytes + 255) & ~(size_t)255;
    return p;
  };
  u16*   xb    = (u16*)alloc((size_t)TSEQ * DIMM * 2);
  u16*   wb    = (u16*)alloc((size_t)4 * DIMM * DIMM * 2);
  float* qkv   = (float*)alloc((size_t)TSEQ * 3 * DIMM * 4);
  u16*   Qg    = (u16*)alloc((size_t)NH * TSEQ * HD * 2);
  u16*   Kg    = (u16*)alloc((size_t)NH * TSEQ * HD * 2);
  u16*   Vtmp  = (u16*)alloc((size_t)NH * TSEQ * HD * 2);
  u16*   VTg   = (u16*)alloc((size_t)NH * HD * TSEQ * 2);
  float* gateA = (float*)alloc((size_t)NH * TSEQ * 4);
  u16*   Yg    = (u16*)alloc((size_t)TSEQ * DIMM * 2);

  k_convert<<<2048, 256, 0, stream>>>(x, qkvo, lam, xb, wb);
  k_gemm_nt<<<dim3(24, 24), 256, 0, stream>>>(xb, wb, qkv, TSEQ, 3 * DIMM, DIMM);
  k_prep<<<NH * TSEQ / 4, 256, 0, stream>>>(qkv, x, ve, cosb, sinb, gwa, gwv, Qg, Kg, Vtmp, gateA);
  k_vtrans<<<dim3(TSEQ / 64, HD / 64, NH), 256, 0, stream>>>(Vtmp, VTg);
  k_attn<<<dim3(TSEQ / QBLK, NH), 128, 0, stream>>>(Qg, Kg, VTg, gateA, seg, bm, Yg);
  k_gemm_nt<<<dim3(DIMM / 128, 24), 256, 0, stream>>>(Yg, wb + (size_t)3 * DIMM * DIMM, out, TSEQ, DIMM, DIMM);
}